// Round 10
// baseline (246.011 us; speedup 1.0000x reference)
//
#include <hip/hip_runtime.h>
#include <math.h>

// Quantized causal attention on int8 MFMA — R16.
// R15 post-mortem: P1 pair-tiles landed (attn 120->118.5, total 235.1 best,
// no spills). Mechanism confirmed: fewer/fatter barrier intervals at fixed
// register shape. R16 applies the SAME pattern to P2, which still pays
// 3 barriers/tile x 16 = 48 (majority of sync points):
//  - Stage V-tile PAIR (8 b128 bursts) + 256 const rows + both vs-groups;
//    requant tile A -> pcsA and tile B -> pcsB back-to-back (pcs now a
//    double buffer, so no barrier between); one barrier; PV A; PV B.
//    3 barriers/pair instead of 6. P2 barriers 48 -> ~27.
//  - LDS ~73.2KB (q8s 9.2 + un 36.9 + pcs-pair 18.4 + consts) -> still
//    2 blocks/CU. Register shape unchanged. P1 = R15 verbatim.
// Tripwires: WRITE_SIZE >= 40MB = spill -> revert; attn >= 120us = P2
// pairing refuted -> R15 is the structural floor.

#define S_LEN 2048
#define BATCH 2
#define NH    16
#define HD    128
#define RSTR  4096   // floats between seq positions
#define SCALE2 (0.08838834764831845f * 1.4426950408889634f)   // (1/sqrt(128))/ln2
#define EXP2F(x) __builtin_amdgcn_exp2f(x)

typedef int v4i __attribute__((ext_vector_type(4)));
#define MFMA16(a,b,c) __builtin_amdgcn_mfma_i32_16x16x64_i8((a),(b),(c),0,0,0)

// ws byte offsets
#define WS_K8   0u
#define WS_V8T  (8u*1024u*1024u)
#define WS_SK   (16u*1024u*1024u)
#define WS_GSV  (WS_SK + 256u*1024u)

__device__ __forceinline__ int sbsum(unsigned p) {
    return (int)(signed char)(p) + (int)(signed char)(p>>8)
         + (int)(signed char)(p>>16) + (int)(signed char)(p>>24);
}

// ---- fused prep: V transpose+GSV (blocks 0..511, heavy, first) ----
// ----             K pack+SKs       (blocks 512..1535)             ----
__global__ __launch_bounds__(256) void prep(
    const float* __restrict__ K, const float* __restrict__ V,
    signed char* __restrict__ K8, float* __restrict__ SKs,
    signed char* __restrict__ V8T, float* __restrict__ GSV)
{
    __shared__ int v8i[128*33];
    const int tid = threadIdx.x;
    const int bx  = blockIdx.x;
    if (bx >= 512) {
        const int base = (bx - 512)*2048 + tid;       // 1024 blocks x 256 x 8
        #pragma unroll
        for (int rep = 0; rep < 8; ++rep) {
            int idx = base + rep*256;                 // float4 index
            float4 x = *(const float4*)(K + (size_t)idx*4);
            int a=(int)x.x, b=(int)x.y, c=(int)x.z, d=(int)x.w;
            ((int*)K8)[idx] = (a&255)|((b&255)<<8)|((c&255)<<16)|((d&255)<<24);
            float s = x.x + x.y + x.z + x.w;
            #pragma unroll
            for (int off = 16; off >= 1; off >>= 1) s += __shfl_xor(s, off);
            if ((tid & 31) == 0) SKs[idx >> 5] = s;
        }
    } else {
        const int bid = bx;
        const int bh = bid & 31, ck = bid >> 5;   // ck = 128-t chunk = v-group
        const int b = bh >> 4, h = bh & 15;
        const int t0 = ck * 128;
        const int boff = b*2048 + h*128;
        #pragma unroll
        for (int it = 0; it < 16; ++it) {
            int idx = tid + it*256;
            int t = idx >> 5, dw = idx & 31;
            float4 x = *(const float4*)(V + (size_t)(t0+t)*RSTR + boff + 4*dw);
            int a=(int)x.x, b2=(int)x.y, c=(int)x.z, d=(int)x.w;
            v8i[t*33 + dw] = (a&255)|((b2&255)<<8)|((c&255)<<16)|((d&255)<<24);
        }
        __syncthreads();
        #pragma unroll
        for (int it = 0; it < 4; ++it) {
            int j = tid + it*256;
            int tg = j & 31, dw = j >> 5;
            unsigned r0 = (unsigned)v8i[(4*tg+0)*33 + dw];
            unsigned r1 = (unsigned)v8i[(4*tg+1)*33 + dw];
            unsigned r2 = (unsigned)v8i[(4*tg+2)*33 + dw];
            unsigned r3 = (unsigned)v8i[(4*tg+3)*33 + dw];
            unsigned x01 = __builtin_amdgcn_perm(r1, r0, 0x05010400u);
            unsigned x23 = __builtin_amdgcn_perm(r3, r2, 0x05010400u);
            unsigned y01 = __builtin_amdgcn_perm(r1, r0, 0x07030602u);
            unsigned y23 = __builtin_amdgcn_perm(r3, r2, 0x07030602u);
            unsigned p[4];
            p[0] = __builtin_amdgcn_perm(x23, x01, 0x05040100u);
            p[1] = __builtin_amdgcn_perm(x23, x01, 0x07060302u);
            p[2] = __builtin_amdgcn_perm(y23, y01, 0x05040100u);
            p[3] = __builtin_amdgcn_perm(y23, y01, 0x07060302u);
            int s[4];
            #pragma unroll
            for (int jj = 0; jj < 4; ++jj) {
                int d = 4*dw + jj;
                *(int*)(V8T + ((size_t)bh*128 + d)*2048 + t0 + 4*tg) = (int)p[jj];
                s[jj] = sbsum(p[jj]);
            }
            #pragma unroll
            for (int off = 1; off < 32; off <<= 1) {
                #pragma unroll
                for (int jj = 0; jj < 4; ++jj) s[jj] += __shfl_xor(s[jj], off);
            }
            if (tg == 0) {
                #pragma unroll
                for (int jj = 0; jj < 4; ++jj)
                    GSV[((size_t)bh*16 + ck)*128 + 4*dw + jj] = (float)s[jj];
            }
        }
    }
}

// ---- main kernel ----
__global__ __launch_bounds__(256, 2) void attn_main(
    const float* __restrict__ Q,
    const signed char* __restrict__ K8, const signed char* __restrict__ V8T,
    const float* __restrict__ QMN, const float* __restrict__ QSC,
    const float* __restrict__ KMN, const float* __restrict__ KSC,
    const float* __restrict__ VMN, const float* __restrict__ VSC,
    const float* __restrict__ SKs, const float* __restrict__ GSV,
    const int* __restrict__ CAUSAL, float* __restrict__ OUT)
{
    __shared__ __align__(16) signed char q8s[64*144];   // [q][d] int8
    __shared__ __align__(16) signed char un[256*144];   // P1: K pair | P2: V pair
    __shared__ __align__(16) signed char pcs[2*64*144]; // P2 code pair
    __shared__ float rs_c1[64], rs_c2[64], rs_c3[64];
    __shared__ float rs_mx[64], rs_den[64], rs_mn[64];
    __shared__ float rs_u1[64], rs_w1[64], rs_psc[64], rs_pmn[64];
    __shared__ float ktA[256], ktB[256], ktC[256];      // pair consts
    __shared__ float vsA[2][128], vsB[2][128];          // vs, vm (pair groups)
    __shared__ float vsumL[128], cgsL[128];             // VSUM / CGS row

    signed char* k8u = un;              // Phase-1 alias (K pair tile)

    const int tid  = threadIdx.x;
    const int w    = tid >> 6;
    const int lane = tid & 63;
    const int n    = lane & 15;
    const int quad = lane >> 4;
    const int bhi  = blockIdx.x & 31;
    const int qt   = 31 - (int)(blockIdx.x >> 5);   // heavy tiles first
    const int b    = bhi >> 4, h = bhi & 15;
    const int causal = *CAUSAL;
    const int s0   = qt * 64;
    const int boff = b*2048 + h*128;
    const v4i vzero = {0,0,0,0};
    const v4i ones  = {0x01010101,0x01010101,0x01010101,0x01010101};

    // ---- stage Q tile (float -> int8 LDS) + per-row consts ----
    #pragma unroll
    for (int it = 0; it < 8; ++it) {
        int idx = tid + it*256;
        int row = idx >> 5, d4 = (idx & 31) << 2;
        float4 x = *(const float4*)(Q + (size_t)(s0+row)*RSTR + boff + d4);
        int a=(int)x.x, b2=(int)x.y, c=(int)x.z, d=(int)x.w;
        *(int*)(q8s + row*144 + d4) = (a&255)|((b2&255)<<8)|((c&255)<<16)|((d&255)<<24);
    }
    if (tid < 64) {
        int si = (s0 + tid)*32 + bhi;
        rs_c1[tid] = QSC[si]; rs_c2[tid] = QMN[si];
    }
    __syncthreads();

    const int kt_end = causal ? ((s0 + 63) >> 7) : 15;

    v4i a0p = *(const v4i*)(q8s + (16*w + n)*144 + 16*quad);
    v4i a1p = *(const v4i*)(q8s + (16*w + n)*144 + 64 + 16*quad);

    // Q token sums via one MFMA-ones pair -> rs_c3 (prep never reads Q)
    {
        v4i qsum = MFMA16(a0p, ones, vzero);
        qsum = MFMA16(a1p, ones, qsum);
        if (n == 0) {
            #pragma unroll
            for (int r = 0; r < 4; ++r) {
                int qq = 16*w + 4*quad + r;
                rs_c3[qq] = fmaf(rs_c1[qq], (float)qsum[r], 128.0f*rs_c2[qq]);
            }
        }
    }
    __syncthreads();

    float c1r[4], c2r[4], c3r[4]; int qgr[4];
    #pragma unroll
    for (int r = 0; r < 4; ++r) {
        int qq = 16*w + 4*quad + r;
        c1r[r] = rs_c1[qq]; c2r[r] = rs_c2[qq]; c3r[r] = rs_c3[qq];
        qgr[r] = s0 + qq;
    }

    float m[4], l[4], mn[4];
    #pragma unroll
    for (int r = 0; r < 4; ++r) { m[r] = -INFINITY; l[r] = 0.f; mn[r] = INFINITY; }

    // ================= Phase 1: softmax stats, pair-tiles (R15) ==============
#define P1_STAGE_PAIR(KTP)                                                       \
    const int t0g = (KTP) * 256;                                                 \
    __syncthreads();                                                             \
    _Pragma("unroll")                                                            \
    for (int it = 0; it < 8; ++it) {                                             \
        int idx = tid + it*256;                                                  \
        int trow = idx >> 3, doff = (idx & 7) << 4;                              \
        *(uint4*)(k8u + trow*144 + doff) =                                       \
            *(const uint4*)(K8 + ((size_t)(t0g+trow)*32 + bhi)*128 + doff);      \
    }                                                                            \
    {                                                                            \
        int si = (t0g + tid)*32 + bhi;                                           \
        ktA[tid] = KSC[si]*SCALE2; ktB[tid] = KMN[si]*SCALE2; ktC[tid] = SKs[si];\
    }                                                                            \
    __syncthreads();

#define P1_STAGE_ONE(KT)                                                         \
    const int t0g = (KT) * 128;                                                  \
    __syncthreads();                                                             \
    _Pragma("unroll")                                                            \
    for (int it = 0; it < 4; ++it) {                                             \
        int idx = tid + it*256;                                                  \
        int trow = idx >> 3, doff = (idx & 7) << 4;                              \
        *(uint4*)(k8u + trow*144 + doff) =                                       \
            *(const uint4*)(K8 + ((size_t)(t0g+trow)*32 + bhi)*128 + doff);      \
    }                                                                            \
    if (tid < 128) {                                                             \
        int si = (t0g + tid)*32 + bhi;                                           \
        ktA[tid] = KSC[si]*SCALE2; ktB[tid] = KMN[si]*SCALE2; ktC[tid] = SKs[si];\
    }                                                                            \
    __syncthreads();

#define P1_COMP(OFS, MASKED)                                                     \
  {                                                                              \
    float tmax[4], sarr[8][4];                                                   \
    _Pragma("unroll")                                                            \
    for (int r = 0; r < 4; ++r) tmax[r] = -INFINITY;                             \
    _Pragma("unroll")                                                            \
    for (int tb = 0; tb < 8; ++tb) {                                             \
        v4i b0 = *(const v4i*)(k8u + ((OFS) + 16*tb + n)*144 + 16*quad);         \
        v4i b1 = *(const v4i*)(k8u + ((OFS) + 16*tb + n)*144 + 64 + 16*quad);    \
        v4i acc = MFMA16(a0p, b0, vzero);                                        \
        acc = MFMA16(a1p, b1, acc);                                              \
        int tl = (OFS) + 16*tb + n;                                              \
        float kA = ktA[tl], kB = ktB[tl], kC = ktC[tl];                          \
        _Pragma("unroll")                                                        \
        for (int r = 0; r < 4; ++r) {                                            \
            float Sf = (float)acc[r];                                            \
            float sv = fmaf(kA, fmaf(c1r[r], Sf, c2r[r]*kC), kB*c3r[r]);         \
            if (MASKED) sv = (t0g + tl > qgr[r]) ? -INFINITY : sv;               \
            sarr[tb][r] = sv;                                                    \
            tmax[r] = fmaxf(tmax[r], sv);                                        \
            mn[r] = fminf(mn[r], sv);                                            \
        }                                                                        \
    }                                                                            \
    _Pragma("unroll")                                                            \
    for (int r = 0; r < 4; ++r) {                                                \
        float mm = fmaxf(m[r], tmax[r]);                                         \
        if (mm > -INFINITY) {                                                    \
            float e0 = EXP2F(sarr[0][r]-mm) + EXP2F(sarr[1][r]-mm);              \
            float e1 = EXP2F(sarr[2][r]-mm) + EXP2F(sarr[3][r]-mm);              \
            float e2 = EXP2F(sarr[4][r]-mm) + EXP2F(sarr[5][r]-mm);              \
            float e3 = EXP2F(sarr[6][r]-mm) + EXP2F(sarr[7][r]-mm);              \
            l[r] = fmaf(l[r], EXP2F(m[r]-mm), (e0+e1)+(e2+e3));                  \
            m[r] = mm;                                                           \
        }                                                                        \
    }                                                                            \
  }

    {
        const int T = kt_end + 1;                       // tiles to process
        const int fullp = (T & 1) ? (T >> 1) : ((T >> 1) - 1);
        for (int ktp = 0; ktp < fullp; ++ktp) {
            P1_STAGE_PAIR(ktp);
            P1_COMP(0, false);
            P1_COMP(128, false);
        }
        if (T & 1) {                                    // leftover single tile
            P1_STAGE_ONE(kt_end);
            if (causal) { P1_COMP(0, true); } else { P1_COMP(0, false); }
        } else {                                        // final pair, 2nd masked
            P1_STAGE_PAIR(fullp);
            P1_COMP(0, false);
            if (causal) { P1_COMP(128, true); } else { P1_COMP(128, false); }
        }
    }

    // reduce stats across the 16 col-lanes
    #pragma unroll
    for (int r = 0; r < 4; ++r) {
        #pragma unroll
        for (int off = 1; off < 16; off <<= 1) {
            float m2 = __shfl_xor(m[r], off);
            float l2 = __shfl_xor(l[r], off);
            float n2 = __shfl_xor(mn[r], off);
            float mm = fmaxf(m[r], m2);
            if (mm > -INFINITY) l[r] = l[r]*EXP2F(m[r]-mm) + l2*EXP2F(m2-mm);
            m[r] = mm;
            mn[r] = fminf(mn[r], n2);
        }
        if (n == 0) {
            int qq = 16*w + 4*quad + r;
            rs_mx[qq] = m[r]; rs_den[qq] = l[r]; rs_mn[qq] = mn[r];
        }
    }
    __syncthreads();   // all P1 reads of un done before P2 overwrites
    if (tid < 64) {
        float mx = rs_mx[tid], den = rs_den[tid], mnv = rs_mn[tid];
        float invd = 1.0f/den;
        int s = s0 + tid;
        bool hasmask = (causal != 0) && (s < S_LEN-1);
        float pmin = hasmask ? 0.0f : EXP2F(mnv - mx)*invd;
        float psc  = (invd - pmin)/255.0f + 1e-12f;
        float ipsc = 1.0f/psc;
        rs_u1[tid] = invd*ipsc; rs_w1[tid] = -pmin*ipsc;
        rs_psc[tid] = psc; rs_pmn[tid] = pmin;
    } else if (tid >= 128) {
        // in-block VSUM (full row) + CGS (cumulative to kt_end) for this bh
        int d = tid - 128;
        float vsum = 0.f, cgs = 0.f;
        #pragma unroll
        for (int g = 0; g < 16; ++g) {
            float gs = GSV[((size_t)bhi*16 + g)*128 + d];
            int vi = ((g*BATCH + b)*NH + h)*HD + d;
            float vs = VSC[vi], vm = VMN[vi];
            vsum = fmaf(vs, gs, fmaf(128.0f, vm, vsum));
            if (g <= kt_end) cgs = fmaf(128.0f*vs, gs, fmaf(16384.0f, vm, cgs));
        }
        vsumL[d] = vsum; cgsL[d] = cgs;
    }
    __syncthreads();

    // ---- hoist P2 tile-invariants: Q B-fragments + per-q constants ----
    v4i qb0[4], qb1[4];
    float qc1[4], qc2[4], qc3[4], qmxn[4], qu1[4], qw1[4];
    int qgq[4];
    #pragma unroll
    for (int cb = 0; cb < 4; ++cb) {
        int qcol = 16*cb + n;
        qb0[cb] = *(const v4i*)(q8s + qcol*144 + 16*quad);
        qb1[cb] = *(const v4i*)(q8s + qcol*144 + 64 + 16*quad);
        qc1[cb] = rs_c1[qcol]; qc2[cb] = rs_c2[qcol]; qc3[cb] = rs_c3[qcol];
        qmxn[cb] = -rs_mx[qcol]; qu1[cb] = rs_u1[qcol]; qw1[cb] = rs_w1[qcol];
        qgq[cb] = s0 + qcol;
    }

    // ================= Phase 2: requant + PV, pair-tiles =================
    float outa[4][8];
    #pragma unroll
    for (int r = 0; r < 4; ++r)
        #pragma unroll
        for (int db = 0; db < 8; ++db) outa[r][db] = 0.f;

#define P2_STAGE_PAIR(KTP)                                                       \
    const int t0g = (KTP) * 256;                                                 \
    __syncthreads();   /* previous PV reads done */                              \
    _Pragma("unroll")                                                            \
    for (int it = 0; it < 8; ++it) {                                             \
        int idx = tid + it*256;                                                  \
        int half = idx >> 10;                                                    \
        int j = idx & 1023;                                                      \
        int trow = j >> 3, doff = (j & 7) << 4;                                  \
        *(uint4*)(un + half*(128*144) + trow*144 + doff) =                       \
            *(const uint4*)(V8T + ((size_t)bhi*128 + trow)*2048                  \
                            + t0g + half*128 + doff);                            \
    }                                                                            \
    {                                                                            \
        int si = (t0g + tid)*32 + bhi;                                           \
        ktA[tid] = KSC[si]*SCALE2; ktB[tid] = KMN[si]*SCALE2; ktC[tid] = SKs[si];\
        int half = tid >> 7, d = tid & 127;                                      \
        int g = 2*(KTP) + half;                                                  \
        int vi = ((g*BATCH + b)*NH + h)*HD + d;                                  \
        vsA[half][d] = VSC[vi]; vsB[half][d] = VMN[vi];                          \
    }                                                                            \
    __syncthreads();

#define P2_STAGE_ONE(KT)                                                         \
    const int t0g = (KT) * 128;                                                  \
    __syncthreads();   /* previous PV reads done */                              \
    _Pragma("unroll")                                                            \
    for (int it = 0; it < 4; ++it) {                                             \
        int idx = tid + it*256;                                                  \
        int trow = idx >> 3, doff = (idx & 7) << 4;                              \
        *(uint4*)(un + trow*144 + doff) =                                        \
            *(const uint4*)(V8T + ((size_t)bhi*128 + trow)*2048 + t0g + doff);   \
    }                                                                            \
    if (tid < 128) {                                                             \
        int si = (t0g + tid)*32 + bhi;                                           \
        ktA[tid] = KSC[si]*SCALE2; ktB[tid] = KMN[si]*SCALE2; ktC[tid] = SKs[si];\
    } else {                                                                     \
        int d = tid - 128;                                                       \
        int vi = (((KT)*BATCH + b)*NH + h)*HD + d;                               \
        vsA[0][d] = VSC[vi]; vsB[0][d] = VMN[vi];                                \
    }                                                                            \
    __syncthreads();

#define P2_REQUANT(HALF, MASKED)                                                 \
  {                                                                              \
    const int tb0 = t0g + (HALF)*128;                                            \
    signed char* pcx = pcs + (HALF)*(64*144);                                    \
    _Pragma("unroll")                                                            \
    for (int rb = 0; rb < 2; ++rb) {                                             \
        int trow = 32*w + 16*rb;                                                 \
        const signed char* kp = K8 + ((size_t)(tb0+trow+n)*32 + bhi)*128         \
                                   + 16*quad;                                    \
        v4i a0 = *(const v4i*)kp;          /* A-operand direct from global */    \
        v4i a1 = *(const v4i*)(kp + 64);                                         \
        float ksr[4], kmr[4], skr[4];                                            \
        int tgb = tb0 + trow + 4*quad;                                           \
        _Pragma("unroll")                                                        \
        for (int r = 0; r < 4; ++r) {                                            \
            int tl = (HALF)*128 + trow + 4*quad + r;                             \
            ksr[r] = ktA[tl]; kmr[r] = ktB[tl]; skr[r] = ktC[tl];                \
        }                                                                        \
        _Pragma("unroll")                                                        \
        for (int cb = 0; cb < 4; ++cb) {                                         \
            v4i acc = MFMA16(a0, qb0[cb], vzero);                                \
            acc = MFMA16(a1, qb1[cb], acc);                                      \
            int cby[4];                                                          \
            _Pragma("unroll")                                                    \
            for (int r = 0; r < 4; ++r) {                                        \
                float Sf = (float)acc[r];                                        \
                float x = fmaf(ksr[r], fmaf(qc1[cb], Sf, qc2[cb]*skr[r]),        \
                               fmaf(kmr[r], qc3[cb], qmxn[cb]));                 \
                if (MASKED) x = (tgb + r > qgq[cb]) ? -INFINITY : x;             \
                float e = EXP2F(x);                                              \
                float f = fmaf(e, qu1[cb], qw1[cb]) + 8388608.0f; /* RNE int */  \
                cby[r] = __float_as_int(f);                                      \
            }                                                                    \
            unsigned t01 = __builtin_amdgcn_perm((unsigned)cby[1],               \
                                                 (unsigned)cby[0], 0x00000400u); \
            unsigned t23 = __builtin_amdgcn_perm((unsigned)cby[3],               \
                                                 (unsigned)cby[2], 0x04000000u); \
            int packed = (int)(__builtin_amdgcn_perm(t23, t01, 0x07060100u)      \
                               ^ 0x80808080u);  /* code - 128 per byte */        \
            *(int*)(pcx + (16*cb + n)*144 + trow + 4*quad) = packed;             \
        }                                                                        \
    }                                                                            \
  }

#define P2_PV(HALF)                                                              \
  {                                                                              \
    const signed char* pcx = pcs + (HALF)*(64*144);                              \
    const signed char* vx  = un + (HALF)*(128*144);                              \
    v4i a0 = *(const v4i*)(pcx + (16*w + n)*144 + 16*quad);                      \
    v4i a1 = *(const v4i*)(pcx + (16*w + n)*144 + 64 + 16*quad);                 \
    v4i c1a = MFMA16(a0, ones, vzero);                                           \
    c1a = MFMA16(a1, ones, c1a);                                                 \
    float c1f[4];                                                                \
    _Pragma("unroll")                                                            \
    for (int r = 0; r < 4; ++r) c1f[r] = (float)c1a[r];                          \
    _Pragma("unroll")                                                            \
    for (int db = 0; db < 8; ++db) {                                             \
        v4i b0 = *(const v4i*)(vx + (16*db + n)*144 + 16*quad);                  \
        v4i b1 = *(const v4i*)(vx + (16*db + n)*144 + 64 + 16*quad);             \
        v4i cv = MFMA16(a0, b0, vzero);                                          \
        cv = MFMA16(a1, b1, cv);                                                 \
        int d = 16*db + n;                                                       \
        float vs = vsA[HALF][d], vm = vsB[HALF][d];                              \
        _Pragma("unroll")                                                        \
        for (int r = 0; r < 4; ++r)                                              \
            outa[r][db] = fmaf(vs, (float)cv[r],                                 \
                               fmaf(vm, c1f[r], outa[r][db]));                   \
    }                                                                            \
  }

    {
        const int T = kt_end + 1;                       // tiles to process
        const int fullp = (T & 1) ? (T >> 1) : ((T >> 1) - 1);
        for (int ktp = 0; ktp < fullp; ++ktp) {
            P2_STAGE_PAIR(ktp);
            P2_REQUANT(0, false);
            P2_REQUANT(1, false);
            __syncthreads();
            P2_PV(0);
            P2_PV(1);
        }
        if (T & 1) {                                    // leftover single tile
            P2_STAGE_ONE(kt_end);
            if (causal) { P2_REQUANT(0, true); } else { P2_REQUANT(0, false); }
            __syncthreads();
            P2_PV(0);
        } else {                                        // final pair, 2nd masked
            P2_STAGE_PAIR(fullp);
            P2_REQUANT(0, false);
            if (causal) { P2_REQUANT(1, true); } else { P2_REQUANT(1, false); }
            __syncthreads();
            P2_PV(0);
            P2_PV(1);
        }
    }

    // ---- epilogue: out = psc*(outa + cgs) + pmin*vsum ----
    float pscr[4], pmnr[4];
    #pragma unroll
    for (int r = 0; r < 4; ++r) {
        int qq = 16*w + 4*quad + r;
        pscr[r] = rs_psc[qq]; pmnr[r] = rs_pmn[qq];
    }
    #pragma unroll
    for (int db = 0; db < 8; ++db) {
        int d = 16*db + n;
        float vsum = vsumL[d];
        float cgs  = cgsL[d];
        #pragma unroll
        for (int r = 0; r < 4; ++r) {
            int s = s0 + 16*w + 4*quad + r;
            OUT[(size_t)s*RSTR + boff + d] = fmaf(pscr[r], outa[r][db] + cgs, pmnr[r]*vsum);
        }
    }
}

extern "C" void kernel_launch(void* const* d_in, const int* in_sizes, int n_in,
                              void* d_out, int out_size, void* d_ws, size_t ws_size,
                              hipStream_t stream) {
    (void)in_sizes; (void)n_in; (void)out_size; (void)ws_size;
    const float* Q   = (const float*)d_in[0];
    const float* K   = (const float*)d_in[1];
    const float* V   = (const float*)d_in[2];
    const float* QMN = (const float*)d_in[3];
    const float* QSC = (const float*)d_in[4];
    const float* KMN = (const float*)d_in[5];
    const float* KSC = (const float*)d_in[6];
    const float* VMN = (const float*)d_in[7];
    const float* VSC = (const float*)d_in[8];
    const int*   CS  = (const int*)d_in[9];
    float* out = (float*)d_out;

    char* ws = (char*)d_ws;
    signed char* K8  = (signed char*)(ws + WS_K8);
    signed char* V8T = (signed char*)(ws + WS_V8T);
    float* SKs  = (float*)(ws + WS_SK);
    float* GSVp = (float*)(ws + WS_GSV);

    prep<<<1536, 256, 0, stream>>>(K, V, K8, SKs, V8T, GSVp);
    attn_main<<<1024, 256, 0, stream>>>(Q, K8, V8T, QMN, QSC, KMN, KSC, VMN, VSC,
                                        SKs, GSVp, CS, out);
}

// Round 11
// 234.519 us; speedup vs baseline: 1.0490x; 1.0490x over previous
//
#include <hip/hip_runtime.h>
#include <math.h>

// Quantized causal attention on int8 MFMA — R17 (= R15, locked best).
// R16 post-mortem: P2 pair-tiles refuted (126.2us, no spill — schedule
// degradation: P2's 3-barrier form already interleaves stage/requant;
// merging tiles serialized a double staging burst and lengthened the
// pcs->PV window). Per pre-commitment, R15 is this structure's floor.
// Session ledger: wins = lean prep (R10/R11), fused prep (R13), P1
// pair-tiles (R15). Refuted with counters = forced occupancy (R7/R9/R12),
// phase split (R12), intra-wave prefetch (R13), MFMA-ones in tile path
// (R10), P2 pairing (R16). attn_main 118.5us latency-bound at the
// 4x-confirmed 2-block/CU register wall; gap ~117us = ~20us roofline prep
// + ~95us fixed overhead. R17 re-submits the measured best (235.1us).

#define S_LEN 2048
#define BATCH 2
#define NH    16
#define HD    128
#define RSTR  4096   // floats between seq positions
#define SCALE2 (0.08838834764831845f * 1.4426950408889634f)   // (1/sqrt(128))/ln2
#define EXP2F(x) __builtin_amdgcn_exp2f(x)

typedef int v4i __attribute__((ext_vector_type(4)));
#define MFMA16(a,b,c) __builtin_amdgcn_mfma_i32_16x16x64_i8((a),(b),(c),0,0,0)

// ws byte offsets
#define WS_K8   0u
#define WS_V8T  (8u*1024u*1024u)
#define WS_SK   (16u*1024u*1024u)
#define WS_GSV  (WS_SK + 256u*1024u)

__device__ __forceinline__ int sbsum(unsigned p) {
    return (int)(signed char)(p) + (int)(signed char)(p>>8)
         + (int)(signed char)(p>>16) + (int)(signed char)(p>>24);
}

// ---- fused prep: V transpose+GSV (blocks 0..511, heavy, first) ----
// ----             K pack+SKs       (blocks 512..1535)             ----
__global__ __launch_bounds__(256) void prep(
    const float* __restrict__ K, const float* __restrict__ V,
    signed char* __restrict__ K8, float* __restrict__ SKs,
    signed char* __restrict__ V8T, float* __restrict__ GSV)
{
    __shared__ int v8i[128*33];
    const int tid = threadIdx.x;
    const int bx  = blockIdx.x;
    if (bx >= 512) {
        const int base = (bx - 512)*2048 + tid;       // 1024 blocks x 256 x 8
        #pragma unroll
        for (int rep = 0; rep < 8; ++rep) {
            int idx = base + rep*256;                 // float4 index
            float4 x = *(const float4*)(K + (size_t)idx*4);
            int a=(int)x.x, b=(int)x.y, c=(int)x.z, d=(int)x.w;
            ((int*)K8)[idx] = (a&255)|((b&255)<<8)|((c&255)<<16)|((d&255)<<24);
            float s = x.x + x.y + x.z + x.w;
            #pragma unroll
            for (int off = 16; off >= 1; off >>= 1) s += __shfl_xor(s, off);
            if ((tid & 31) == 0) SKs[idx >> 5] = s;
        }
    } else {
        const int bid = bx;
        const int bh = bid & 31, ck = bid >> 5;   // ck = 128-t chunk = v-group
        const int b = bh >> 4, h = bh & 15;
        const int t0 = ck * 128;
        const int boff = b*2048 + h*128;
        #pragma unroll
        for (int it = 0; it < 16; ++it) {
            int idx = tid + it*256;
            int t = idx >> 5, dw = idx & 31;
            float4 x = *(const float4*)(V + (size_t)(t0+t)*RSTR + boff + 4*dw);
            int a=(int)x.x, b2=(int)x.y, c=(int)x.z, d=(int)x.w;
            v8i[t*33 + dw] = (a&255)|((b2&255)<<8)|((c&255)<<16)|((d&255)<<24);
        }
        __syncthreads();
        #pragma unroll
        for (int it = 0; it < 4; ++it) {
            int j = tid + it*256;
            int tg = j & 31, dw = j >> 5;
            unsigned r0 = (unsigned)v8i[(4*tg+0)*33 + dw];
            unsigned r1 = (unsigned)v8i[(4*tg+1)*33 + dw];
            unsigned r2 = (unsigned)v8i[(4*tg+2)*33 + dw];
            unsigned r3 = (unsigned)v8i[(4*tg+3)*33 + dw];
            unsigned x01 = __builtin_amdgcn_perm(r1, r0, 0x05010400u);
            unsigned x23 = __builtin_amdgcn_perm(r3, r2, 0x05010400u);
            unsigned y01 = __builtin_amdgcn_perm(r1, r0, 0x07030602u);
            unsigned y23 = __builtin_amdgcn_perm(r3, r2, 0x07030602u);
            unsigned p[4];
            p[0] = __builtin_amdgcn_perm(x23, x01, 0x05040100u);
            p[1] = __builtin_amdgcn_perm(x23, x01, 0x07060302u);
            p[2] = __builtin_amdgcn_perm(y23, y01, 0x05040100u);
            p[3] = __builtin_amdgcn_perm(y23, y01, 0x07060302u);
            int s[4];
            #pragma unroll
            for (int jj = 0; jj < 4; ++jj) {
                int d = 4*dw + jj;
                *(int*)(V8T + ((size_t)bh*128 + d)*2048 + t0 + 4*tg) = (int)p[jj];
                s[jj] = sbsum(p[jj]);
            }
            #pragma unroll
            for (int off = 1; off < 32; off <<= 1) {
                #pragma unroll
                for (int jj = 0; jj < 4; ++jj) s[jj] += __shfl_xor(s[jj], off);
            }
            if (tg == 0) {
                #pragma unroll
                for (int jj = 0; jj < 4; ++jj)
                    GSV[((size_t)bh*16 + ck)*128 + 4*dw + jj] = (float)s[jj];
            }
        }
    }
}

// ---- main kernel ----
__global__ __launch_bounds__(256, 2) void attn_main(
    const float* __restrict__ Q,
    const signed char* __restrict__ K8, const signed char* __restrict__ V8T,
    const float* __restrict__ QMN, const float* __restrict__ QSC,
    const float* __restrict__ KMN, const float* __restrict__ KSC,
    const float* __restrict__ VMN, const float* __restrict__ VSC,
    const float* __restrict__ SKs, const float* __restrict__ GSV,
    const int* __restrict__ CAUSAL, float* __restrict__ OUT)
{
    __shared__ __align__(16) signed char q8s[64*144];   // [q][d] int8
    __shared__ __align__(16) signed char un[256*144];   // P1: K pair [256][144] | P2: v8s+pcs
    __shared__ float rs_c1[64], rs_c2[64], rs_c3[64];
    __shared__ float rs_mx[64], rs_den[64], rs_mn[64];
    __shared__ float rs_u1[64], rs_w1[64], rs_psc[64], rs_pmn[64];
    __shared__ float ktA[256], ktB[256], ktC[256];      // ks*S2, km*S2, sk8
    __shared__ float vsA[128], vsB[128];                // vs, vm (current group)
    __shared__ float vsumL[128], cgsL[128];             // in-block VSUM / CGS row

    signed char* k8u = un;              // Phase-1 alias (K pair tile)
    signed char* v8s = un;              // Phase-2 alias (V [d][t])
    signed char* pcs = un + 128*144;    // Phase-2 alias (codes [q][t])

    const int tid  = threadIdx.x;
    const int w    = tid >> 6;
    const int lane = tid & 63;
    const int n    = lane & 15;
    const int quad = lane >> 4;
    const int bhi  = blockIdx.x & 31;
    const int qt   = 31 - (int)(blockIdx.x >> 5);   // heavy tiles first
    const int b    = bhi >> 4, h = bhi & 15;
    const int causal = *CAUSAL;
    const int s0   = qt * 64;
    const int boff = b*2048 + h*128;
    const v4i vzero = {0,0,0,0};
    const v4i ones  = {0x01010101,0x01010101,0x01010101,0x01010101};

    // ---- stage Q tile (float -> int8 LDS) + per-row consts ----
    #pragma unroll
    for (int it = 0; it < 8; ++it) {
        int idx = tid + it*256;
        int row = idx >> 5, d4 = (idx & 31) << 2;
        float4 x = *(const float4*)(Q + (size_t)(s0+row)*RSTR + boff + d4);
        int a=(int)x.x, b2=(int)x.y, c=(int)x.z, d=(int)x.w;
        *(int*)(q8s + row*144 + d4) = (a&255)|((b2&255)<<8)|((c&255)<<16)|((d&255)<<24);
    }
    if (tid < 64) {
        int si = (s0 + tid)*32 + bhi;
        rs_c1[tid] = QSC[si]; rs_c2[tid] = QMN[si];
    }
    __syncthreads();

    const int kt_end = causal ? ((s0 + 63) >> 7) : 15;

    v4i a0p = *(const v4i*)(q8s + (16*w + n)*144 + 16*quad);
    v4i a1p = *(const v4i*)(q8s + (16*w + n)*144 + 64 + 16*quad);

    // Q token sums via one MFMA-ones pair -> rs_c3 (prep never reads Q)
    {
        v4i qsum = MFMA16(a0p, ones, vzero);
        qsum = MFMA16(a1p, ones, qsum);
        if (n == 0) {
            #pragma unroll
            for (int r = 0; r < 4; ++r) {
                int qq = 16*w + 4*quad + r;
                rs_c3[qq] = fmaf(rs_c1[qq], (float)qsum[r], 128.0f*rs_c2[qq]);
            }
        }
    }
    __syncthreads();

    float c1r[4], c2r[4], c3r[4]; int qgr[4];
    #pragma unroll
    for (int r = 0; r < 4; ++r) {
        int qq = 16*w + 4*quad + r;
        c1r[r] = rs_c1[qq]; c2r[r] = rs_c2[qq]; c3r[r] = rs_c3[qq];
        qgr[r] = s0 + qq;
    }

    float m[4], l[4], mn[4];
    #pragma unroll
    for (int r = 0; r < 4; ++r) { m[r] = -INFINITY; l[r] = 0.f; mn[r] = INFINITY; }

    // ================= Phase 1: softmax stats, pair-tiles =================
    // Stage 256 t-rows + 256 consts per burst, compute 2 tiles back-to-back.
#define P1_STAGE_PAIR(KTP)                                                       \
    const int t0g = (KTP) * 256;                                                 \
    __syncthreads();                                                             \
    _Pragma("unroll")                                                            \
    for (int it = 0; it < 8; ++it) {                                             \
        int idx = tid + it*256;                                                  \
        int trow = idx >> 3, doff = (idx & 7) << 4;                              \
        *(uint4*)(k8u + trow*144 + doff) =                                       \
            *(const uint4*)(K8 + ((size_t)(t0g+trow)*32 + bhi)*128 + doff);      \
    }                                                                            \
    {                                                                            \
        int si = (t0g + tid)*32 + bhi;                                           \
        ktA[tid] = KSC[si]*SCALE2; ktB[tid] = KMN[si]*SCALE2; ktC[tid] = SKs[si];\
    }                                                                            \
    __syncthreads();

#define P1_STAGE_ONE(KT)                                                         \
    const int t0g = (KT) * 128;                                                  \
    __syncthreads();                                                             \
    _Pragma("unroll")                                                            \
    for (int it = 0; it < 4; ++it) {                                             \
        int idx = tid + it*256;                                                  \
        int trow = idx >> 3, doff = (idx & 7) << 4;                              \
        *(uint4*)(k8u + trow*144 + doff) =                                       \
            *(const uint4*)(K8 + ((size_t)(t0g+trow)*32 + bhi)*128 + doff);      \
    }                                                                            \
    if (tid < 128) {                                                             \
        int si = (t0g + tid)*32 + bhi;                                           \
        ktA[tid] = KSC[si]*SCALE2; ktB[tid] = KMN[si]*SCALE2; ktC[tid] = SKs[si];\
    }                                                                            \
    __syncthreads();

#define P1_COMP(OFS, MASKED)                                                     \
  {                                                                              \
    float tmax[4], sarr[8][4];                                                   \
    _Pragma("unroll")                                                            \
    for (int r = 0; r < 4; ++r) tmax[r] = -INFINITY;                             \
    _Pragma("unroll")                                                            \
    for (int tb = 0; tb < 8; ++tb) {                                             \
        v4i b0 = *(const v4i*)(k8u + ((OFS) + 16*tb + n)*144 + 16*quad);         \
        v4i b1 = *(const v4i*)(k8u + ((OFS) + 16*tb + n)*144 + 64 + 16*quad);    \
        v4i acc = MFMA16(a0p, b0, vzero);                                        \
        acc = MFMA16(a1p, b1, acc);                                              \
        int tl = (OFS) + 16*tb + n;                                              \
        float kA = ktA[tl], kB = ktB[tl], kC = ktC[tl];                          \
        _Pragma("unroll")                                                        \
        for (int r = 0; r < 4; ++r) {                                            \
            float Sf = (float)acc[r];                                            \
            float sv = fmaf(kA, fmaf(c1r[r], Sf, c2r[r]*kC), kB*c3r[r]);         \
            if (MASKED) sv = (t0g + tl > qgr[r]) ? -INFINITY : sv;               \
            sarr[tb][r] = sv;                                                    \
            tmax[r] = fmaxf(tmax[r], sv);                                        \
            mn[r] = fminf(mn[r], sv);                                            \
        }                                                                        \
    }                                                                            \
    _Pragma("unroll")                                                            \
    for (int r = 0; r < 4; ++r) {                                                \
        float mm = fmaxf(m[r], tmax[r]);                                         \
        if (mm > -INFINITY) {                                                    \
            float e0 = EXP2F(sarr[0][r]-mm) + EXP2F(sarr[1][r]-mm);              \
            float e1 = EXP2F(sarr[2][r]-mm) + EXP2F(sarr[3][r]-mm);              \
            float e2 = EXP2F(sarr[4][r]-mm) + EXP2F(sarr[5][r]-mm);              \
            float e3 = EXP2F(sarr[6][r]-mm) + EXP2F(sarr[7][r]-mm);              \
            l[r] = fmaf(l[r], EXP2F(m[r]-mm), (e0+e1)+(e2+e3));                  \
            m[r] = mm;                                                           \
        }                                                                        \
    }                                                                            \
  }

    {
        const int T = kt_end + 1;                       // tiles to process
        const int fullp = (T & 1) ? (T >> 1) : ((T >> 1) - 1);
        for (int ktp = 0; ktp < fullp; ++ktp) {
            P1_STAGE_PAIR(ktp);
            P1_COMP(0, false);
            P1_COMP(128, false);
        }
        if (T & 1) {                                    // leftover single tile
            P1_STAGE_ONE(kt_end);
            if (causal) { P1_COMP(0, true); } else { P1_COMP(0, false); }
        } else {                                        // final pair, 2nd masked
            P1_STAGE_PAIR(fullp);
            P1_COMP(0, false);
            if (causal) { P1_COMP(128, true); } else { P1_COMP(128, false); }
        }
    }

    // reduce stats across the 16 col-lanes
    #pragma unroll
    for (int r = 0; r < 4; ++r) {
        #pragma unroll
        for (int off = 1; off < 16; off <<= 1) {
            float m2 = __shfl_xor(m[r], off);
            float l2 = __shfl_xor(l[r], off);
            float n2 = __shfl_xor(mn[r], off);
            float mm = fmaxf(m[r], m2);
            if (mm > -INFINITY) l[r] = l[r]*EXP2F(m[r]-mm) + l2*EXP2F(m2-mm);
            m[r] = mm;
            mn[r] = fminf(mn[r], n2);
        }
        if (n == 0) {
            int qq = 16*w + 4*quad + r;
            rs_mx[qq] = m[r]; rs_den[qq] = l[r]; rs_mn[qq] = mn[r];
        }
    }
    __syncthreads();   // all P1 reads of un done before P2 overwrites
    if (tid < 64) {
        float mx = rs_mx[tid], den = rs_den[tid], mnv = rs_mn[tid];
        float invd = 1.0f/den;
        int s = s0 + tid;
        bool hasmask = (causal != 0) && (s < S_LEN-1);
        float pmin = hasmask ? 0.0f : EXP2F(mnv - mx)*invd;
        float psc  = (invd - pmin)/255.0f + 1e-12f;
        float ipsc = 1.0f/psc;
        rs_u1[tid] = invd*ipsc; rs_w1[tid] = -pmin*ipsc;
        rs_psc[tid] = psc; rs_pmn[tid] = pmin;
    } else if (tid >= 128) {
        // in-block VSUM (full row) + CGS (cumulative to kt_end) for this bh
        int d = tid - 128;
        float vsum = 0.f, cgs = 0.f;
        #pragma unroll
        for (int g = 0; g < 16; ++g) {
            float gs = GSV[((size_t)bhi*16 + g)*128 + d];
            int vi = ((g*BATCH + b)*NH + h)*HD + d;
            float vs = VSC[vi], vm = VMN[vi];
            vsum = fmaf(vs, gs, fmaf(128.0f, vm, vsum));
            if (g <= kt_end) cgs = fmaf(128.0f*vs, gs, fmaf(16384.0f, vm, cgs));
        }
        vsumL[d] = vsum; cgsL[d] = cgs;
    }
    __syncthreads();

    // ---- hoist P2 tile-invariants: Q B-fragments + per-q constants ----
    v4i qb0[4], qb1[4];
    float qc1[4], qc2[4], qc3[4], qmxn[4], qu1[4], qw1[4];
    int qgq[4];
    #pragma unroll
    for (int cb = 0; cb < 4; ++cb) {
        int qcol = 16*cb + n;
        qb0[cb] = *(const v4i*)(q8s + qcol*144 + 16*quad);
        qb1[cb] = *(const v4i*)(q8s + qcol*144 + 64 + 16*quad);
        qc1[cb] = rs_c1[qcol]; qc2[cb] = rs_c2[qcol]; qc3[cb] = rs_c3[qcol];
        qmxn[cb] = -rs_mx[qcol]; qu1[cb] = rs_u1[qcol]; qw1[cb] = rs_w1[qcol];
        qgq[cb] = s0 + qcol;
    }

    // ================= Phase 2: requant + PV (R14 verbatim) =================
    float outa[4][8];
    #pragma unroll
    for (int r = 0; r < 4; ++r)
        #pragma unroll
        for (int db = 0; db < 8; ++db) outa[r][db] = 0.f;

#define P2_TILE(MASKED)                                                          \
  do {                                                                           \
    const int t0g = kt * 128;                                                    \
    __syncthreads();   /* previous PV reads of v8s/pcs done */                   \
    _Pragma("unroll")                                                            \
    for (int it = 0; it < 4; ++it) {                                             \
        int idx = tid + it*256;                                                  \
        int trow = idx >> 3, doff = (idx & 7) << 4;                              \
        *(uint4*)(v8s + trow*144 + doff) =                                       \
            *(const uint4*)(V8T + ((size_t)bhi*128 + trow)*2048 + t0g + doff);   \
    }                                                                            \
    if (tid < 128) {                                                             \
        int si = (t0g + tid)*32 + bhi;                                           \
        ktA[tid] = KSC[si]*SCALE2; ktB[tid] = KMN[si]*SCALE2; ktC[tid] = SKs[si];\
    } else {                                                                     \
        int d = tid - 128;                                                       \
        int vi = ((kt*BATCH + b)*NH + h)*HD + d;                                 \
        vsA[d] = VSC[vi]; vsB[d] = VMN[vi];                                      \
    }                                                                            \
    __syncthreads();                                                             \
    _Pragma("unroll")                                                            \
    for (int rb = 0; rb < 2; ++rb) {                                             \
        int trow = 32*w + 16*rb;                                                 \
        const signed char* kp = K8 + ((size_t)(t0g+trow+n)*32 + bhi)*128         \
                                   + 16*quad;                                    \
        v4i a0 = *(const v4i*)kp;          /* A-operand direct from global */    \
        v4i a1 = *(const v4i*)(kp + 64);                                         \
        float ksr[4], kmr[4], skr[4];                                            \
        int tgb = t0g + trow + 4*quad;                                           \
        _Pragma("unroll")                                                        \
        for (int r = 0; r < 4; ++r) {                                            \
            int tl = trow + 4*quad + r;                                          \
            ksr[r] = ktA[tl]; kmr[r] = ktB[tl]; skr[r] = ktC[tl];                \
        }                                                                        \
        _Pragma("unroll")                                                        \
        for (int cb = 0; cb < 4; ++cb) {                                         \
            v4i acc = MFMA16(a0, qb0[cb], vzero);                                \
            acc = MFMA16(a1, qb1[cb], acc);                                      \
            int cby[4];                                                          \
            _Pragma("unroll")                                                    \
            for (int r = 0; r < 4; ++r) {                                        \
                float Sf = (float)acc[r];                                        \
                float x = fmaf(ksr[r], fmaf(qc1[cb], Sf, qc2[cb]*skr[r]),        \
                               fmaf(kmr[r], qc3[cb], qmxn[cb]));                 \
                if (MASKED) x = (tgb + r > qgq[cb]) ? -INFINITY : x;             \
                float e = EXP2F(x);                                              \
                float f = fmaf(e, qu1[cb], qw1[cb]) + 8388608.0f; /* RNE int */  \
                cby[r] = __float_as_int(f);                                      \
            }                                                                    \
            unsigned t01 = __builtin_amdgcn_perm((unsigned)cby[1],               \
                                                 (unsigned)cby[0], 0x00000400u); \
            unsigned t23 = __builtin_amdgcn_perm((unsigned)cby[3],               \
                                                 (unsigned)cby[2], 0x04000000u); \
            int packed = (int)(__builtin_amdgcn_perm(t23, t01, 0x07060100u)      \
                               ^ 0x80808080u);  /* code - 128 per byte */        \
            *(int*)(pcs + (16*cb + n)*144 + trow + 4*quad) = packed;             \
        }                                                                        \
    }                                                                            \
    __syncthreads();                                                             \
    {                                                                            \
        v4i a0 = *(const v4i*)(pcs + (16*w + n)*144 + 16*quad);                  \
        v4i a1 = *(const v4i*)(pcs + (16*w + n)*144 + 64 + 16*quad);             \
        v4i c1a = MFMA16(a0, ones, vzero);                                       \
        c1a = MFMA16(a1, ones, c1a);                                             \
        float c1f[4];                                                            \
        _Pragma("unroll")                                                        \
        for (int r = 0; r < 4; ++r) c1f[r] = (float)c1a[r];                      \
        _Pragma("unroll")                                                        \
        for (int db = 0; db < 8; ++db) {                                         \
            v4i b0 = *(const v4i*)(v8s + (16*db + n)*144 + 16*quad);             \
            v4i b1 = *(const v4i*)(v8s + (16*db + n)*144 + 64 + 16*quad);        \
            v4i cv = MFMA16(a0, b0, vzero);                                      \
            cv = MFMA16(a1, b1, cv);                                             \
            int d = 16*db + n;                                                   \
            float vs = vsA[d], vm = vsB[d];                                      \
            _Pragma("unroll")                                                    \
            for (int r = 0; r < 4; ++r)                                          \
                outa[r][db] = fmaf(vs, (float)cv[r],                             \
                                   fmaf(vm, c1f[r], outa[r][db]));               \
        }                                                                        \
    }                                                                            \
  } while (0)

    {
        int kt;
        for (kt = 0; kt < kt_end; ++kt) P2_TILE(false);
        kt = kt_end;
        if (causal) P2_TILE(true); else P2_TILE(false);
    }

    // ---- epilogue: out = psc*(outa + cgs) + pmin*vsum ----
    float pscr[4], pmnr[4];
    #pragma unroll
    for (int r = 0; r < 4; ++r) {
        int qq = 16*w + 4*quad + r;
        pscr[r] = rs_psc[qq]; pmnr[r] = rs_pmn[qq];
    }
    #pragma unroll
    for (int db = 0; db < 8; ++db) {
        int d = 16*db + n;
        float vsum = vsumL[d];
        float cgs  = cgsL[d];
        #pragma unroll
        for (int r = 0; r < 4; ++r) {
            int s = s0 + 16*w + 4*quad + r;
            OUT[(size_t)s*RSTR + boff + d] = fmaf(pscr[r], outa[r][db] + cgs, pmnr[r]*vsum);
        }
    }
}

extern "C" void kernel_launch(void* const* d_in, const int* in_sizes, int n_in,
                              void* d_out, int out_size, void* d_ws, size_t ws_size,
                              hipStream_t stream) {
    (void)in_sizes; (void)n_in; (void)out_size; (void)ws_size;
    const float* Q   = (const float*)d_in[0];
    const float* K   = (const float*)d_in[1];
    const float* V   = (const float*)d_in[2];
    const float* QMN = (const float*)d_in[3];
    const float* QSC = (const float*)d_in[4];
    const float* KMN = (const float*)d_in[5];
    const float* KSC = (const float*)d_in[6];
    const float* VMN = (const float*)d_in[7];
    const float* VSC = (const float*)d_in[8];
    const int*   CS  = (const int*)d_in[9];
    float* out = (float*)d_out;

    char* ws = (char*)d_ws;
    signed char* K8  = (signed char*)(ws + WS_K8);
    signed char* V8T = (signed char*)(ws + WS_V8T);
    float* SKs  = (float*)(ws + WS_SK);
    float* GSVp = (float*)(ws + WS_GSV);

    prep<<<1536, 256, 0, stream>>>(K, V, K8, SKs, V8T, GSVp);
    attn_main<<<1024, 256, 0, stream>>>(Q, K8, V8T, QMN, QSC, KMN, KSC, VMN, VSC,
                                        SKs, GSVp, CS, out);
}